// Round 1
// baseline (1271.485 us; speedup 1.0000x reference)
//
#include <hip/hip_runtime.h>
#include <hip/hip_bf16.h>
#include <math.h>

// Problem: B=4, L=1024, D=1024, H=16, HD=64, SCALE=1/8
// scores[b,h,l,r] = (q.k + q.e[l-r] + k.e[l-r]) * SCALE, softmax over r, @V.
// e[d] = dist_emb[l - r + 1023].

#define Bq 4
#define Lq 1024
#define Dq 1024
#define Hq 16
#define HDq 64
#define BHq (Bq * Hq)          // 64
#define HEAD_ELEMS ((size_t)BHq * Lq * HDq)   // 4194304 per tensor (q,k,v)

// ---------------------------------------------------------------------------
// K1: QKV projection GEMM.  X[4096,1024] @ W[1024,3072] + bias
// Output scattered into ws as q/k/v each in [bh=b*16+h][l][d] layout.
// 128x128 tile, BK=8, 256 threads, 8x8 micro-tile per thread.
// ---------------------------------------------------------------------------
#define TILE 128
#define GBK 8

__global__ __launch_bounds__(256) void qkv_gemm(
    const float* __restrict__ X, const float* __restrict__ W,
    const float* __restrict__ bias, float* __restrict__ ws) {
  __shared__ float As[GBK][TILE];   // As[k][m] (transposed stage)
  __shared__ float Bs[GBK][TILE];   // Bs[k][n]

  const int tid = threadIdx.x;
  const int bn = blockIdx.x * TILE;   // n block (0..3071)
  const int bm = blockIdx.y * TILE;   // m block (0..4095)
  const int tx = tid & 15;            // n dir
  const int ty = tid >> 4;            // m dir

  const int a_row = tid >> 1;         // m_local 0..127
  const int a_col = (tid & 1) * 4;    // k offset 0 or 4
  const int b_row = tid >> 5;         // k_local 0..7
  const int b_col = (tid & 31) * 4;   // n offset

  float acc[8][8];
#pragma unroll
  for (int i = 0; i < 8; i++)
#pragma unroll
    for (int j = 0; j < 8; j++) acc[i][j] = 0.f;

  for (int k0 = 0; k0 < Dq; k0 += GBK) {
    // prefetch to registers (no LDS dependency)
    float4 av = *(const float4*)(X + (size_t)(bm + a_row) * Dq + k0 + a_col);
    float4 bv = *(const float4*)(W + (size_t)(k0 + b_row) * (3 * Dq) + bn + b_col);
    __syncthreads();   // previous iteration's compute reads done
    As[a_col + 0][a_row] = av.x;
    As[a_col + 1][a_row] = av.y;
    As[a_col + 2][a_row] = av.z;
    As[a_col + 3][a_row] = av.w;
    *(float4*)&Bs[b_row][b_col] = bv;
    __syncthreads();

#pragma unroll
    for (int kk = 0; kk < GBK; kk++) {
      float4 a0 = *(const float4*)&As[kk][ty * 8];
      float4 a1 = *(const float4*)&As[kk][ty * 8 + 4];
      float4 b0 = *(const float4*)&Bs[kk][tx * 8];
      float4 b1 = *(const float4*)&Bs[kk][tx * 8 + 4];
      float am[8] = {a0.x, a0.y, a0.z, a0.w, a1.x, a1.y, a1.z, a1.w};
      float bn8[8] = {b0.x, b0.y, b0.z, b0.w, b1.x, b1.y, b1.z, b1.w};
#pragma unroll
      for (int i = 0; i < 8; i++)
#pragma unroll
        for (int j = 0; j < 8; j++) acc[i][j] = fmaf(am[i], bn8[j], acc[i][j]);
    }
  }

  // epilogue: add bias, scatter to q/k/v [bh][l][d] layout
  const int n_base = bn + tx * 8;          // 8 cols, within one (t,h) block
  const int t = n_base / 1024;             // 0=q 1=k 2=v
  const int c = n_base & 1023;
  const int h = c >> 6;
  const int d0 = c & 63;
  float* dst_base = ws + (size_t)t * HEAD_ELEMS;
  float b8[8];
#pragma unroll
  for (int j = 0; j < 8; j++) b8[j] = bias[n_base + j];

#pragma unroll
  for (int i = 0; i < 8; i++) {
    const int m = bm + ty * 8 + i;
    const int b = m >> 10;
    const int l = m & 1023;
    float* dst = dst_base + (((size_t)(b * Hq + h) * Lq + l) * HDq + d0);
    float4 o0 = {acc[i][0] + b8[0], acc[i][1] + b8[1], acc[i][2] + b8[2], acc[i][3] + b8[3]};
    float4 o1 = {acc[i][4] + b8[4], acc[i][5] + b8[5], acc[i][6] + b8[6], acc[i][7] + b8[7]};
    *(float4*)(dst) = o0;
    *(float4*)(dst + 4) = o1;
  }
}

// ---------------------------------------------------------------------------
// K2: fused attention with relative-position bias, online softmax.
// One thread per query row. Block = 128 threads = 128 rows. Chunk = 32 cols.
// ---------------------------------------------------------------------------
#define ROWS 128
#define CK 32
#define EROWS 159            // ROWS + CK - 1 e-band rows per chunk
#define ESTRIDE 66           // float stride, 2-way bank alias (free)

__global__ __launch_bounds__(128) void attn_kernel(
    const float* __restrict__ ws, const float* __restrict__ dist_emb,
    float* __restrict__ out) {
  __shared__ float k_lds[CK][HDq];             // 8 KB
  __shared__ float v_lds[CK][HDq];             // 8 KB
  __shared__ float e_lds[EROWS * ESTRIDE + 8]; // ~42 KB

  const int bh = blockIdx.x;                   // 0..63
  const int l0 = blockIdx.y * ROWS;
  const int tid = threadIdx.x;
  const int l = l0 + tid;

  const float* Qp = ws + ((size_t)bh * Lq + l) * HDq;
  const float* Kp = ws + HEAD_ELEMS + (size_t)bh * Lq * HDq;
  const float* Vp = ws + 2 * HEAD_ELEMS + (size_t)bh * Lq * HDq;

  float4 q[16];
#pragma unroll
  for (int j = 0; j < 16; j++) q[j] = ((const float4*)Qp)[j];

  float4 acc[16];
#pragma unroll
  for (int j = 0; j < 16; j++) acc[j] = make_float4(0.f, 0.f, 0.f, 0.f);
  float mrun = -1e30f;
  float lsum = 0.f;

  for (int cc = 0; cc < Lq / CK; cc++) {
    const int r0 = cc * CK;
    __syncthreads();  // previous chunk's LDS reads complete

    // stage K/V chunk: CK*64 floats each = 512 float4 / 128 threads = 4 each
#pragma unroll
    for (int i = 0; i < 4; i++) {
      int idx = tid + i * 128;
      int row = idx >> 4;
      int c4 = idx & 15;
      ((float4*)k_lds[row])[c4] = ((const float4*)(Kp + (size_t)(r0 + row) * HDq))[c4];
      ((float4*)v_lds[row])[c4] = ((const float4*)(Vp + (size_t)(r0 + row) * HDq))[c4];
    }
    // stage e band: rows delta = l - r for l in [l0,l0+128), r in [r0,r0+32)
    // emb row = (l - r) + 1023 ; first = l0 - (r0+CK-1) + 1023
    const int dlo = l0 - r0 + (1023 - (CK - 1));
    for (int i = tid; i < EROWS * 16; i += 128) {
      int row = i >> 4;
      int c4 = i & 15;
      float4 ev = ((const float4*)(dist_emb + (size_t)(dlo + row) * HDq))[c4];
      float* ep = e_lds + row * ESTRIDE + c4 * 4;
      ep[0] = ev.x; ep[1] = ev.y; ep[2] = ev.z; ep[3] = ev.w;
    }
    __syncthreads();

    for (int rl = 0; rl < CK; rl++) {
      const float4* kr = (const float4*)k_lds[rl];
      const float4* vr = (const float4*)v_lds[rl];
      const float2* er = (const float2*)(e_lds + (tid + (CK - 1) - rl) * ESTRIDE);
      float s1a = 0.f, s1b = 0.f, s2a = 0.f, s2b = 0.f;
#pragma unroll
      for (int j = 0; j < 16; j++) {
        float4 kk = kr[j];
        float2 e0 = er[2 * j];
        float2 e1 = er[2 * j + 1];
        s1a = fmaf(q[j].x, kk.x, s1a);
        s2a = fmaf(q[j].x + kk.x, e0.x, s2a);
        s1b = fmaf(q[j].y, kk.y, s1b);
        s2b = fmaf(q[j].y + kk.y, e0.y, s2b);
        s1a = fmaf(q[j].z, kk.z, s1a);
        s2a = fmaf(q[j].z + kk.z, e1.x, s2a);
        s1b = fmaf(q[j].w, kk.w, s1b);
        s2b = fmaf(q[j].w + kk.w, e1.y, s2b);
      }
      const float s = (s1a + s1b + s2a + s2b) * 0.125f;
      const float mnew = fmaxf(mrun, s);
      const float p = __expf(s - mnew);
      if (mnew > mrun) {
        const float alpha = __expf(mrun - mnew);
        lsum *= alpha;
#pragma unroll
        for (int j = 0; j < 16; j++) {
          acc[j].x *= alpha; acc[j].y *= alpha;
          acc[j].z *= alpha; acc[j].w *= alpha;
        }
        mrun = mnew;
      }
      lsum += p;
#pragma unroll
      for (int j = 0; j < 16; j++) {
        float4 vv = vr[j];
        acc[j].x = fmaf(p, vv.x, acc[j].x);
        acc[j].y = fmaf(p, vv.y, acc[j].y);
        acc[j].z = fmaf(p, vv.z, acc[j].z);
        acc[j].w = fmaf(p, vv.w, acc[j].w);
      }
    }
  }

  const float inv = 1.0f / lsum;
  const int b = bh >> 4;
  const int h = bh & 15;
  // out layout [B, L, H, HD]
  float* op = out + (((size_t)(b * Lq + l) * Hq) + h) * HDq;
#pragma unroll
  for (int j = 0; j < 16; j++) {
    float4 o = acc[j];
    o.x *= inv; o.y *= inv; o.z *= inv; o.w *= inv;
    ((float4*)op)[j] = o;
  }
}

// ---------------------------------------------------------------------------
extern "C" void kernel_launch(void* const* d_in, const int* in_sizes, int n_in,
                              void* d_out, int out_size, void* d_ws, size_t ws_size,
                              hipStream_t stream) {
  const float* x        = (const float*)d_in[0];   // [4,1024,1024]
  const float* Wqkv     = (const float*)d_in[1];   // [1024,3072]
  const float* bqkv     = (const float*)d_in[2];   // [3072]
  const float* dist_emb = (const float*)d_in[3];   // [2047,64]
  float* out = (float*)d_out;                      // [4,1024,1024]
  float* ws  = (float*)d_ws;                       // q,k,v : 48 MB

  dim3 g1(3 * Dq / TILE, (Bq * Lq) / TILE);  // (24, 32)
  qkv_gemm<<<g1, dim3(256), 0, stream>>>(x, Wqkv, bqkv, ws);

  dim3 g2(BHq, Lq / ROWS);                   // (64, 8)
  attn_kernel<<<g2, dim3(ROWS), 0, stream>>>(ws, dist_emb, out);
}

// Round 3
// 588.160 us; speedup vs baseline: 2.1618x; 2.1618x over previous
//
#include <hip/hip_runtime.h>
#include <hip/hip_bf16.h>
#include <math.h>

// B=4, L=1024, D=1024, H=16, HD=64, SCALE=1/8
// scores[l,r] = (q.k + q.e[l-r] + k.e[l-r]) * SCALE; softmax over r; @V.
#define Bq 4
#define Lq 1024
#define Dq 1024
#define Hq 16
#define HDq 64
#define BHq (Bq * Hq)
#define HEAD_ELEMS ((size_t)BHq * Lq * HDq)   // 4194304 floats per tensor

typedef short bf16x8 __attribute__((ext_vector_type(8)));
typedef float f32x4 __attribute__((ext_vector_type(4)));
#define MFMA16(A, B, C) __builtin_amdgcn_mfma_f32_16x16x32_bf16(A, B, C, 0, 0, 0)

__device__ __forceinline__ unsigned short f2bf(float x) {
  unsigned u = __builtin_bit_cast(unsigned, x);
  unsigned r = u + 0x7FFFu + ((u >> 16) & 1u);   // RNE (finite inputs)
  return (unsigned short)(r >> 16);
}
__device__ __forceinline__ float bf2f(unsigned short s) {
  unsigned u = ((unsigned)s) << 16;
  return __builtin_bit_cast(float, u);
}

// ---------------------------------------------------------------------------
// K1: QKV projection GEMM (fp32, unchanged known-good from R1).
// X[4096,1024] @ W[1024,3072] + bias -> q/k/v each [bh][l][64] fp32 in ws.
// ---------------------------------------------------------------------------
#define TILE 128
#define GBK 8

__global__ __launch_bounds__(256) void qkv_gemm(
    const float* __restrict__ X, const float* __restrict__ W,
    const float* __restrict__ bias, float* __restrict__ ws) {
  __shared__ float As[GBK][TILE];
  __shared__ float Bs[GBK][TILE];

  const int tid = threadIdx.x;
  const int bn = blockIdx.x * TILE;
  const int bm = blockIdx.y * TILE;
  const int tx = tid & 15;
  const int ty = tid >> 4;

  const int a_row = tid >> 1;
  const int a_col = (tid & 1) * 4;
  const int b_row = tid >> 5;
  const int b_col = (tid & 31) * 4;

  float acc[8][8];
#pragma unroll
  for (int i = 0; i < 8; i++)
#pragma unroll
    for (int j = 0; j < 8; j++) acc[i][j] = 0.f;

  for (int k0 = 0; k0 < Dq; k0 += GBK) {
    float4 av = *(const float4*)(X + (size_t)(bm + a_row) * Dq + k0 + a_col);
    float4 bv = *(const float4*)(W + (size_t)(k0 + b_row) * (3 * Dq) + bn + b_col);
    __syncthreads();
    As[a_col + 0][a_row] = av.x;
    As[a_col + 1][a_row] = av.y;
    As[a_col + 2][a_row] = av.z;
    As[a_col + 3][a_row] = av.w;
    *(float4*)&Bs[b_row][b_col] = bv;
    __syncthreads();

#pragma unroll
    for (int kk = 0; kk < GBK; kk++) {
      float4 a0 = *(const float4*)&As[kk][ty * 8];
      float4 a1 = *(const float4*)&As[kk][ty * 8 + 4];
      float4 b0 = *(const float4*)&Bs[kk][tx * 8];
      float4 b1 = *(const float4*)&Bs[kk][tx * 8 + 4];
      float am[8] = {a0.x, a0.y, a0.z, a0.w, a1.x, a1.y, a1.z, a1.w};
      float bn8[8] = {b0.x, b0.y, b0.z, b0.w, b1.x, b1.y, b1.z, b1.w};
#pragma unroll
      for (int i = 0; i < 8; i++)
#pragma unroll
        for (int j = 0; j < 8; j++) acc[i][j] = fmaf(am[i], bn8[j], acc[i][j]);
    }
  }

  const int n_base = bn + tx * 8;
  const int t = n_base / 1024;
  const int c = n_base & 1023;
  const int h = c >> 6;
  const int d0 = c & 63;
  float* dst_base = ws + (size_t)t * HEAD_ELEMS;
  float b8[8];
#pragma unroll
  for (int j = 0; j < 8; j++) b8[j] = bias[n_base + j];

#pragma unroll
  for (int i = 0; i < 8; i++) {
    const int m = bm + ty * 8 + i;
    const int b = m >> 10;
    const int l = m & 1023;
    float* dst = dst_base + (((size_t)(b * Hq + h) * Lq + l) * HDq + d0);
    float4 o0 = {acc[i][0] + b8[0], acc[i][1] + b8[1], acc[i][2] + b8[2], acc[i][3] + b8[3]};
    float4 o1 = {acc[i][4] + b8[4], acc[i][5] + b8[5], acc[i][6] + b8[6], acc[i][7] + b8[7]};
    *(float4*)(dst) = o0;
    *(float4*)(dst + 4) = o1;
  }
}

// ---------------------------------------------------------------------------
// K2: V -> VT global, bf16: vtg[bh][d][r]. LDS-tiled transpose (64 rows/block).
// ---------------------------------------------------------------------------
__global__ __launch_bounds__(256) void vt_prep(const float* __restrict__ v,
                                               unsigned short* __restrict__ vtg) {
  __shared__ unsigned short tile[64 * 70];   // stride 70: conflict-free both phases
  const int bh = blockIdx.x, rt = blockIdx.y;
  const int tid = threadIdx.x;
  const float* src = v + ((size_t)bh * Lq + rt * 64) * HDq;
#pragma unroll
  for (int it = 0; it < 4; it++) {
    int idx = tid + it * 256;
    int r = idx >> 4, c4 = idx & 15;
    float4 f = *(const float4*)(src + r * 64 + c4 * 4);
    unsigned w0 = (unsigned)f2bf(f.x) | ((unsigned)f2bf(f.y) << 16);
    unsigned w1 = (unsigned)f2bf(f.z) | ((unsigned)f2bf(f.w) << 16);
    *(unsigned*)&tile[r * 70 + c4 * 4] = w0;       // byte r*140+c4*8 (4-aligned)
    *(unsigned*)&tile[r * 70 + c4 * 4 + 2] = w1;
  }
  __syncthreads();
  unsigned short* dst = vtg + (size_t)bh * HDq * Lq + rt * 64;
#pragma unroll
  for (int it = 0; it < 4; it++) {
    int u = tid + it * 256;
    int d = u >> 4, o8 = u & 15;
    int r4 = o8 * 4;
    unsigned short e0 = tile[(r4 + 0) * 70 + d];
    unsigned short e1 = tile[(r4 + 1) * 70 + d];
    unsigned short e2 = tile[(r4 + 2) * 70 + d];
    unsigned short e3 = tile[(r4 + 3) * 70 + d];
    uint2 pk;
    pk.x = (unsigned)e0 | ((unsigned)e1 << 16);
    pk.y = (unsigned)e2 | ((unsigned)e3 << 16);
    *(uint2*)(dst + (size_t)d * Lq + r4) = pk;     // coalesced per d-row
  }
}

// ---------------------------------------------------------------------------
// K3: dist_emb fp32 -> bf16 copy.
// ---------------------------------------------------------------------------
__global__ __launch_bounds__(256) void emb_prep(const float* __restrict__ e,
                                                unsigned short* __restrict__ o) {
  int i = blockIdx.x * 256 + threadIdx.x;
  if (i < 2047 * 64) o[i] = f2bf(e[i]);
}

// ---------------------------------------------------------------------------
// K4: MFMA flash attention with relative-position bias.
// Block: 256 thr (4 waves), BM=64 q-rows, BN=64 chunk, band=128 delta rows.
// Per chunk: S = Q K^T (MFMA), D1 = Q Pband^T, D2 = K Pband^T (MFMA),
// scatter D1/D2 -> bias1[l][r], bias2[l][r] via delta<->r bijection,
// online softmax in C-layout regs, P through LDS (A-layout), PV MFMA.
// LDS 62976 B (Ps aliases Pband rows 64..127) -> 2 blocks/CU.
// ---------------------------------------------------------------------------
__global__ __launch_bounds__(256, 2) void attn_mfma(
    const float* __restrict__ ws, const unsigned short* __restrict__ vtg,
    const unsigned short* __restrict__ emb, float* __restrict__ out) {
  __shared__ __align__(16) char smem[62976];
  unsigned short* Qs  = (unsigned short*)smem;             // [64][72]
  unsigned short* Ks  = (unsigned short*)(smem + 9216);    // [64][72]
  unsigned short* VTs = (unsigned short*)(smem + 18432);   // [64 d][72]
  unsigned short* Pb  = (unsigned short*)(smem + 27648);   // [128][72]
  unsigned short* Ps  = (unsigned short*)(smem + 36864);   // alias Pb rows 64..127: [64][72]
  unsigned short* B1  = (unsigned short*)(smem + 46080);   // [64][66]
  unsigned short* B2  = (unsigned short*)(smem + 54528);   // [64][66]

  const int bh = blockIdx.x;
  const int l0 = blockIdx.y * 64;
  const int tid = threadIdx.x;
  const int w = tid >> 6, lane = tid & 63;
  const int col = lane & 15, quad = lane >> 4;
  const int lw = w * 16;                      // wave's l-strip AND r-strip base

  const float* Qg = ws + ((size_t)bh * Lq + l0) * HDq;
  const float* Kg = ws + HEAD_ELEMS + (size_t)bh * Lq * HDq;
  const unsigned short* VTgh = vtg + (size_t)bh * HDq * Lq;

  // ---- stage Q once (fp32 -> bf16) ----
#pragma unroll
  for (int it = 0; it < 4; it++) {
    int idx = tid + it * 256;
    int r = idx >> 4, c4 = idx & 15;
    float4 f = *(const float4*)(Qg + r * 64 + c4 * 4);
    uint2 pk;
    pk.x = (unsigned)f2bf(f.x) | ((unsigned)f2bf(f.y) << 16);
    pk.y = (unsigned)f2bf(f.z) | ((unsigned)f2bf(f.w) << 16);
    *(uint2*)&Qs[r * 72 + c4 * 4] = pk;
  }
  __syncthreads();

  // hoisted A-frags for Q (verified layout: A[m=lane&15][k=quad*8+j])
  bf16x8 qf[2];
#pragma unroll
  for (int ks = 0; ks < 2; ks++)
    qf[ks] = *(const bf16x8*)&Qs[(lw + col) * 72 + quad * 8 + ks * 32];

  f32x4 oacc[4];
#pragma unroll
  for (int nt = 0; nt < 4; nt++) oacc[nt] = (f32x4){0.f, 0.f, 0.f, 0.f};
  float mrow[4] = {-1e30f, -1e30f, -1e30f, -1e30f};
  float lrow[4] = {0.f, 0.f, 0.f, 0.f};

  for (int ch = 0; ch < 16; ch++) {
    const int r0 = ch * 64;
    __syncthreads();   // prior chunk's LDS reads complete before restage

    // ---- stage K chunk (fp32 -> bf16) ----
#pragma unroll
    for (int it = 0; it < 4; it++) {
      int idx = tid + it * 256;
      int r = idx >> 4, c4 = idx & 15;
      float4 f = *(const float4*)(Kg + (size_t)(r0 + r) * 64 + c4 * 4);
      uint2 pk;
      pk.x = (unsigned)f2bf(f.x) | ((unsigned)f2bf(f.y) << 16);
      pk.y = (unsigned)f2bf(f.z) | ((unsigned)f2bf(f.w) << 16);
      *(uint2*)&Ks[r * 72 + c4 * 4] = pk;
    }
    // ---- stage VT chunk (bf16 copy from vtg): 64 d-rows x 64 r (4096 el) ----
#pragma unroll
    for (int it = 0; it < 4; it++) {
      int idx = tid + it * 256;          // 1024 units of 8B
      int d = idx >> 4, o8 = idx & 15;
      uint2 val = *(const uint2*)(VTgh + (size_t)d * Lq + r0 + o8 * 4);
      *(uint2*)&VTs[d * 72 + o8 * 4] = val;
    }
    // ---- stage P band (bf16 copy; 128 rows, row j = dist row pb0+j) ----
    const int pb0 = l0 - r0 + 960;       // (l0 - r0 - 63) + 1023, >= 0
#pragma unroll
    for (int it = 0; it < 4; it++) {
      int idx = tid + it * 256;          // 1024 units of 16B
      int row = idx >> 3, o = idx & 7;
      int g = min(pb0 + row, 2046);      // row 127 unused; clamp for safety
      uint4 v4 = *(const uint4*)(emb + (size_t)g * 64 + o * 8);
      *(uint4*)&Pb[row * 72 + o * 8] = v4;
    }
    __syncthreads();   // staging visible

    // ---- S = Q K^T  (B-frag: B[k=quad*8+j][n=lane&15] from K rows) ----
    bf16x8 kf[4][2];
#pragma unroll
    for (int rt = 0; rt < 4; rt++)
#pragma unroll
      for (int ks = 0; ks < 2; ks++)
        kf[rt][ks] = *(const bf16x8*)&Ks[(rt * 16 + col) * 72 + quad * 8 + ks * 32];
    f32x4 sac[4];
#pragma unroll
    for (int rt = 0; rt < 4; rt++) {
      f32x4 z = (f32x4){0.f, 0.f, 0.f, 0.f};
      z = MFMA16(qf[0], kf[rt][0], z);
      z = MFMA16(qf[1], kf[rt][1], z);
      sac[rt] = z;
    }

    // D2 A-frag = wave's own r-strip of K (explicit load; avoids dynamic reg idx)
    bf16x8 kaf[2];
#pragma unroll
    for (int ks = 0; ks < 2; ks++)
      kaf[ks] = *(const bf16x8*)&Ks[(lw + col) * 72 + quad * 8 + ks * 32];

    // ---- D1/D2 GEMMs + scatter into bias1/bias2 ----
#pragma unroll
    for (int dt = 0; dt < 8; dt++) {
      bf16x8 pbf0 = *(const bf16x8*)&Pb[(dt * 16 + col) * 72 + quad * 8];
      bf16x8 pbf1 = *(const bf16x8*)&Pb[(dt * 16 + col) * 72 + quad * 8 + 32];
      f32x4 z = (f32x4){0.f, 0.f, 0.f, 0.f};
      f32x4 y = (f32x4){0.f, 0.f, 0.f, 0.f};
      z = MFMA16(qf[0], pbf0, z);
      z = MFMA16(qf[1], pbf1, z);     // D1[l][delta]
      y = MFMA16(kaf[0], pbf0, y);
      y = MFMA16(kaf[1], pbf1, y);    // D2[r][delta]
      const int dcol = dt * 16 + col; // delta band index j = l - r + 63
#pragma unroll
      for (int k = 0; k < 4; k++) {
        int l1 = lw + quad * 4 + k;
        int r1 = l1 - dcol + 63;
        if (r1 >= 0 && r1 < 64) B1[l1 * 66 + r1] = f2bf(z[k]);
        int r2 = lw + quad * 4 + k;
        int l2 = dcol - 63 + r2;
        if (l2 >= 0 && l2 < 64) B2[l2 * 66 + r2] = f2bf(y[k]);
      }
    }
    __syncthreads();   // bias writes visible (B2 is cross-wave)

    // ---- online softmax (C-layout: row = quad*4+k, col = lane&15) ----
    float p[4][4];
    float alpha[4];
#pragma unroll
    for (int k = 0; k < 4; k++) {
      int l1 = lw + quad * 4 + k;
      float st[4];
#pragma unroll
      for (int rt = 0; rt < 4; rt++) {
        int r = rt * 16 + col;
        float bias = bf2f(B1[l1 * 66 + r]) + bf2f(B2[l1 * 66 + r]);
        st[rt] = (sac[rt][k] + bias) * 0.125f;
      }
      float mx = fmaxf(fmaxf(st[0], st[1]), fmaxf(st[2], st[3]));
      mx = fmaxf(mx, __shfl_xor(mx, 1));
      mx = fmaxf(mx, __shfl_xor(mx, 2));
      mx = fmaxf(mx, __shfl_xor(mx, 4));
      mx = fmaxf(mx, __shfl_xor(mx, 8));
      float mnew = fmaxf(mrow[k], mx);
      float a = __expf(mrow[k] - mnew);
      mrow[k] = mnew;
      alpha[k] = a;
      float ls = 0.f;
#pragma unroll
      for (int rt = 0; rt < 4; rt++) {
        p[rt][k] = __expf(st[rt] - mnew);
        ls += p[rt][k];
      }
      lrow[k] = lrow[k] * a + ls;      // lane-partial sum; reduced at end
    }
#pragma unroll
    for (int nt = 0; nt < 4; nt++)
#pragma unroll
      for (int k = 0; k < 4; k++) oacc[nt][k] *= alpha[k];

    // ---- P -> LDS (A-layout source), same-wave rows only ----
#pragma unroll
    for (int rt = 0; rt < 4; rt++)
#pragma unroll
      for (int k = 0; k < 4; k++)
        Ps[(lw + quad * 4 + k) * 72 + rt * 16 + col] = f2bf(p[rt][k]);

    // ---- PV: O += P @ V  (A = P rows, B = VT rows) ----
    bf16x8 pf[2];
#pragma unroll
    for (int ks = 0; ks < 2; ks++)
      pf[ks] = *(const bf16x8*)&Ps[(lw + col) * 72 + quad * 8 + ks * 32];
#pragma unroll
    for (int nt = 0; nt < 4; nt++) {
      bf16x8 v0 = *(const bf16x8*)&VTs[(nt * 16 + col) * 72 + quad * 8];
      bf16x8 v1 = *(const bf16x8*)&VTs[(nt * 16 + col) * 72 + quad * 8 + 32];
      oacc[nt] = MFMA16(pf[0], v0, oacc[nt]);
      oacc[nt] = MFMA16(pf[1], v1, oacc[nt]);
    }
  }

  // ---- epilogue: normalize and store ----
  float inv[4];
#pragma unroll
  for (int k = 0; k < 4; k++) {
    float t = lrow[k];
    t += __shfl_xor(t, 1);
    t += __shfl_xor(t, 2);
    t += __shfl_xor(t, 4);
    t += __shfl_xor(t, 8);
    inv[k] = 1.0f / t;
  }
  const int b = bh >> 4, h = bh & 15;
#pragma unroll
  for (int nt = 0; nt < 4; nt++) {
#pragma unroll
    for (int k = 0; k < 4; k++) {
      int lg = l0 + lw + quad * 4 + k;
      int d = nt * 16 + col;
      out[(((size_t)b * Lq + lg) * Hq + h) * HDq + d] = oacc[nt][k] * inv[k];
    }
  }
}

// ---------------------------------------------------------------------------
extern "C" void kernel_launch(void* const* d_in, const int* in_sizes, int n_in,
                              void* d_out, int out_size, void* d_ws, size_t ws_size,
                              hipStream_t stream) {
  const float* x        = (const float*)d_in[0];
  const float* Wqkv     = (const float*)d_in[1];
  const float* bqkv     = (const float*)d_in[2];
  const float* dist_emb = (const float*)d_in[3];
  float* out = (float*)d_out;
  float* ws  = (float*)d_ws;
  unsigned short* vtg = (unsigned short*)((char*)d_ws + 50331648);  // 8 MB bf16 V^T
  unsigned short* emb = (unsigned short*)((char*)d_ws + 58720256);  // 256 KB bf16 emb

  emb_prep<<<dim3(512), dim3(256), 0, stream>>>(dist_emb, emb);

  dim3 g1(3 * Dq / TILE, (Bq * Lq) / TILE);
  qkv_gemm<<<g1, dim3(256), 0, stream>>>(x, Wqkv, bqkv, ws);

  vt_prep<<<dim3(BHq, Lq / 64), dim3(256), 0, stream>>>(ws + 2 * HEAD_ELEMS, vtg);

  attn_mfma<<<dim3(BHq, Lq / 64), dim3(256), 0, stream>>>(ws, vtg, emb, out);
}

// Round 4
// 295.946 us; speedup vs baseline: 4.2963x; 1.9874x over previous
//
#include <hip/hip_runtime.h>
#include <hip/hip_bf16.h>
#include <math.h>

// B=4, L=1024, D=1024, H=16, HD=64, SCALE=1/8
// scores[l,r] = (q.k + q.e[l-r] + k.e[l-r]) * SCALE; softmax over r; @V.
#define Bq 4
#define Lq 1024
#define Dq 1024
#define Hq 16
#define HDq 64
#define BHq (Bq * Hq)
#define HEAD_ELEMS ((size_t)BHq * Lq * HDq)   // 4194304 elements per tensor

typedef short bf16x8 __attribute__((ext_vector_type(8)));
typedef _Float16 f16x8 __attribute__((ext_vector_type(8)));
typedef float f32x4 __attribute__((ext_vector_type(4)));
#define MFMA16B(A, B, C) __builtin_amdgcn_mfma_f32_16x16x32_bf16(A, B, C, 0, 0, 0)
#define MFMA16F(A, B, C) __builtin_amdgcn_mfma_f32_16x16x32_f16(A, B, C, 0, 0, 0)

__device__ __forceinline__ unsigned short f2bf(float x) {
  unsigned u = __builtin_bit_cast(unsigned, x);
  unsigned r = u + 0x7FFFu + ((u >> 16) & 1u);   // RNE (finite inputs)
  return (unsigned short)(r >> 16);
}
__device__ __forceinline__ float bf2f(unsigned short s) {
  unsigned u = ((unsigned)s) << 16;
  return __builtin_bit_cast(float, u);
}
__device__ __forceinline__ unsigned short f2h(float x) {
  _Float16 h = (_Float16)x;                      // RNE
  return __builtin_bit_cast(unsigned short, h);
}

// ---------------------------------------------------------------------------
// P1: X fp32 -> fp16 (straight copy).  4096x1024.
// ---------------------------------------------------------------------------
__global__ __launch_bounds__(256) void x_prep(const float* __restrict__ X,
                                              unsigned short* __restrict__ Xh) {
  size_t i = (size_t)blockIdx.x * 256 + threadIdx.x;  // unit of 4 el
  float4 f = *(const float4*)(X + i * 4);
  uint2 pk;
  pk.x = (unsigned)f2h(f.x) | ((unsigned)f2h(f.y) << 16);
  pk.y = (unsigned)f2h(f.z) | ((unsigned)f2h(f.w) << 16);
  *(uint2*)(Xh + i * 4) = pk;
}

// ---------------------------------------------------------------------------
// P2: W fp32 [1024][3072] -> Wt fp16 [3072][1024] (transpose via LDS tile).
// ---------------------------------------------------------------------------
__global__ __launch_bounds__(256) void wt_prep(const float* __restrict__ W,
                                               unsigned short* __restrict__ Wt) {
  __shared__ unsigned short tile[64 * 72];
  const int k0 = blockIdx.x * 64;   // 16
  const int n0 = blockIdx.y * 64;   // 48
  const int tid = threadIdx.x;
#pragma unroll
  for (int it = 0; it < 4; it++) {
    int idx = tid + it * 256;       // 1024 units of 4 el
    int r = idx >> 4, c4 = (idx & 15) * 4;   // r = k row, c4 = n col
    float4 f = *(const float4*)(W + (size_t)(k0 + r) * 3072 + n0 + c4);
    unsigned w0 = (unsigned)f2h(f.x) | ((unsigned)f2h(f.y) << 16);
    unsigned w1 = (unsigned)f2h(f.z) | ((unsigned)f2h(f.w) << 16);
    *(unsigned*)&tile[r * 72 + c4] = w0;
    *(unsigned*)&tile[r * 72 + c4 + 2] = w1;
  }
  __syncthreads();
#pragma unroll
  for (int it = 0; it < 4; it++) {
    int u = tid + it * 256;         // 1024 units of 4 el (k-dir)
    int n = u >> 4, k4 = (u & 15) * 4;
    unsigned short e0 = tile[(k4 + 0) * 72 + n];
    unsigned short e1 = tile[(k4 + 1) * 72 + n];
    unsigned short e2 = tile[(k4 + 2) * 72 + n];
    unsigned short e3 = tile[(k4 + 3) * 72 + n];
    uint2 pk;
    pk.x = (unsigned)e0 | ((unsigned)e1 << 16);
    pk.y = (unsigned)e2 | ((unsigned)e3 << 16);
    *(uint2*)(Wt + (size_t)(n0 + n) * 1024 + k0 + k4) = pk;
  }
}

// ---------------------------------------------------------------------------
// P3: dist_emb fp32 -> bf16.
// ---------------------------------------------------------------------------
__global__ __launch_bounds__(256) void emb_prep(const float* __restrict__ e,
                                                unsigned short* __restrict__ o) {
  int i = blockIdx.x * 256 + threadIdx.x;
  if (i < 2047 * 64) o[i] = f2bf(e[i]);
}

// ---------------------------------------------------------------------------
// K1: QKV projection, fp16 MFMA (m97 structure).
// A = Xh [4096][1024] fp16, B = Wt [3072][1024] fp16 (gemm_bt).
// 128x128 tile, BK=32, 256 thr (4 waves, 2x2 of 64x64), global_load_lds w=16.
// Epilogue: +bias (fp32), -> bf16, LDS transpose for coalesced stores into
// qkvg = q|k|v each [bh][l][64] bf16.
// ---------------------------------------------------------------------------
__global__ __launch_bounds__(256, 2) void qkv_mfma(
    const unsigned short* __restrict__ Xh, const unsigned short* __restrict__ Wt,
    const float* __restrict__ bias, unsigned short* __restrict__ qkvg) {
  __shared__ __align__(16) char smem[32768];
  unsigned short* Asm = (unsigned short*)smem;            // [128][32] (no pad: glds)
  unsigned short* Bsm = (unsigned short*)(smem + 8192);   // [128][32]
  unsigned short* Cs  = (unsigned short*)smem;            // epilogue [128][128]

  const int tid = threadIdx.x;
  const int w = tid >> 6, lane = tid & 63;
  const int col = lane & 15, quad = lane >> 4;
  const int wm = (w >> 1) * 64, wn = (w & 1) * 64;
  const int bn = blockIdx.x * 128, bm = blockIdx.y * 128;

  const unsigned short* Ag = Xh + (size_t)bm * 1024;
  const unsigned short* Bg = Wt + (size_t)bn * 1024;
  const int ldrow = w * 32 + (lane >> 2);   // + it*16
  const int ldoff = (lane & 3) * 8;         // element offset in k

  f32x4 acc[4][4];
#pragma unroll
  for (int i = 0; i < 4; i++)
#pragma unroll
    for (int j = 0; j < 4; j++) acc[i][j] = (f32x4){0.f, 0.f, 0.f, 0.f};

  for (int k0 = 0; k0 < 1024; k0 += 32) {
    __syncthreads();
#pragma unroll
    for (int it = 0; it < 2; it++) {
      const unsigned short* ga = Ag + (size_t)(ldrow + it * 16) * 1024 + k0 + ldoff;
      const unsigned short* gb = Bg + (size_t)(ldrow + it * 16) * 1024 + k0 + ldoff;
      __builtin_amdgcn_global_load_lds(
          (const __attribute__((address_space(1))) unsigned*)ga,
          (__attribute__((address_space(3))) unsigned*)(Asm + (w * 32 + it * 16) * 32),
          16, 0, 0);
      __builtin_amdgcn_global_load_lds(
          (const __attribute__((address_space(1))) unsigned*)gb,
          (__attribute__((address_space(3))) unsigned*)(Bsm + (w * 32 + it * 16) * 32),
          16, 0, 0);
    }
    __syncthreads();
    f16x8 af[4], bf[4];
#pragma unroll
    for (int i = 0; i < 4; i++)
      af[i] = *(const f16x8*)&Asm[(wm + i * 16 + col) * 32 + quad * 8];
#pragma unroll
    for (int j = 0; j < 4; j++)
      bf[j] = *(const f16x8*)&Bsm[(wn + j * 16 + col) * 32 + quad * 8];
#pragma unroll
    for (int i = 0; i < 4; i++)
#pragma unroll
      for (int j = 0; j < 4; j++)
        acc[i][j] = MFMA16F(af[i], bf[j], acc[i][j]);
  }

  float bj[4];
#pragma unroll
  for (int j = 0; j < 4; j++) bj[j] = bias[bn + wn + j * 16 + col];

  __syncthreads();   // staging LDS dead; reuse as Cs
#pragma unroll
  for (int i = 0; i < 4; i++)
#pragma unroll
    for (int j = 0; j < 4; j++)
#pragma unroll
      for (int k = 0; k < 4; k++)
        Cs[(wm + i * 16 + quad * 4 + k) * 128 + wn + j * 16 + col] =
            f2bf(acc[i][j][k] + bj[j]);
  __syncthreads();

  const int t = bn >> 10;                       // uniform per block
  unsigned short* dst_base = qkvg + (size_t)t * HEAD_ELEMS;
#pragma unroll
  for (int it = 0; it < 8; it++) {
    int u = tid + it * 256;                     // 2048 units of 8 el
    int row = u >> 4, c8 = (u & 15) * 8;
    int m = bm + row;
    int n = bn + c8;
    int b = m >> 10, l = m & 1023;
    int cc = n & 1023, h = cc >> 6, d0 = cc & 63;
    uint4 val = *(const uint4*)&Cs[row * 128 + c8];
    *(uint4*)(dst_base + (((size_t)(b * 16 + h) * 1024 + l) * 64 + d0)) = val;
  }
}

// ---------------------------------------------------------------------------
// P4: V bf16 [bh][l][64] -> VT bf16 [bh][d][1024].
// ---------------------------------------------------------------------------
__global__ __launch_bounds__(256) void vt_prep_bf(const unsigned short* __restrict__ vg,
                                                  unsigned short* __restrict__ vtg) {
  __shared__ unsigned short tile[64 * 72];
  const int bh = blockIdx.x;
  const int rt = blockIdx.y * 64;
  const int tid = threadIdx.x;
  const unsigned short* src = vg + ((size_t)bh * Lq + rt) * HDq;
#pragma unroll
  for (int it = 0; it < 2; it++) {
    int idx = tid + it * 256;       // 512 units of 8 el
    int r = idx >> 3, o = (idx & 7) * 8;
    *(uint4*)&tile[r * 72 + o] = *(const uint4*)(src + (size_t)r * 64 + o);
  }
  __syncthreads();
  unsigned short* dst = vtg + (size_t)bh * HDq * Lq;
#pragma unroll
  for (int it = 0; it < 4; it++) {
    int u = tid + it * 256;         // 1024 units of 4 r
    int d = u >> 4, r4 = (u & 15) * 4;
    unsigned short e0 = tile[(r4 + 0) * 72 + d];
    unsigned short e1 = tile[(r4 + 1) * 72 + d];
    unsigned short e2 = tile[(r4 + 2) * 72 + d];
    unsigned short e3 = tile[(r4 + 3) * 72 + d];
    uint2 pk;
    pk.x = (unsigned)e0 | ((unsigned)e1 << 16);
    pk.y = (unsigned)e2 | ((unsigned)e3 << 16);
    *(uint2*)(dst + (size_t)d * Lq + rt + r4) = pk;
  }
}

// ---------------------------------------------------------------------------
// K2: MFMA flash attention with relative-position bias (unchanged structure;
// staging now from bf16 q/k/vt).  LDS 62976 B -> 2 blocks/CU.
// ---------------------------------------------------------------------------
__global__ __launch_bounds__(256, 2) void attn_mfma(
    const unsigned short* __restrict__ qg, const unsigned short* __restrict__ kg,
    const unsigned short* __restrict__ vtg, const unsigned short* __restrict__ emb,
    float* __restrict__ out) {
  __shared__ __align__(16) char smem[62976];
  unsigned short* Qs  = (unsigned short*)smem;             // [64][72]
  unsigned short* Ks  = (unsigned short*)(smem + 9216);    // [64][72]
  unsigned short* VTs = (unsigned short*)(smem + 18432);   // [64 d][72]
  unsigned short* Pb  = (unsigned short*)(smem + 27648);   // [128][72]
  unsigned short* Ps  = (unsigned short*)(smem + 36864);   // alias Pb rows 64..127
  unsigned short* B1  = (unsigned short*)(smem + 46080);   // [64][66]
  unsigned short* B2  = (unsigned short*)(smem + 54528);   // [64][66]

  const int bh = blockIdx.x;
  const int l0 = blockIdx.y * 64;
  const int tid = threadIdx.x;
  const int w = tid >> 6, lane = tid & 63;
  const int col = lane & 15, quad = lane >> 4;
  const int lw = w * 16;

  const unsigned short* Qg = qg + ((size_t)bh * Lq + l0) * HDq;
  const unsigned short* Kg = kg + (size_t)bh * Lq * HDq;
  const unsigned short* VTgh = vtg + (size_t)bh * HDq * Lq;

  // ---- stage Q once (bf16 copy) ----
#pragma unroll
  for (int it = 0; it < 2; it++) {
    int idx = tid + it * 256;       // 512 units of 8 el
    int r = idx >> 3, o = (idx & 7) * 8;
    *(uint4*)&Qs[r * 72 + o] = *(const uint4*)(Qg + (size_t)r * 64 + o);
  }
  __syncthreads();

  bf16x8 qf[2];
#pragma unroll
  for (int ks = 0; ks < 2; ks++)
    qf[ks] = *(const bf16x8*)&Qs[(lw + col) * 72 + quad * 8 + ks * 32];

  f32x4 oacc[4];
#pragma unroll
  for (int nt = 0; nt < 4; nt++) oacc[nt] = (f32x4){0.f, 0.f, 0.f, 0.f};
  float mrow[4] = {-1e30f, -1e30f, -1e30f, -1e30f};
  float lrow[4] = {0.f, 0.f, 0.f, 0.f};

  for (int ch = 0; ch < 16; ch++) {
    const int r0 = ch * 64;
    __syncthreads();

    // ---- stage K chunk (bf16 copy) ----
#pragma unroll
    for (int it = 0; it < 2; it++) {
      int idx = tid + it * 256;
      int r = idx >> 3, o = (idx & 7) * 8;
      *(uint4*)&Ks[r * 72 + o] = *(const uint4*)(Kg + (size_t)(r0 + r) * 64 + o);
    }
    // ---- stage VT chunk ----
#pragma unroll
    for (int it = 0; it < 2; it++) {
      int idx = tid + it * 256;
      int d = idx >> 3, o = (idx & 7) * 8;
      *(uint4*)&VTs[d * 72 + o] = *(const uint4*)(VTgh + (size_t)d * Lq + r0 + o);
    }
    // ---- stage P band ----
    const int pb0 = l0 - r0 + 960;
#pragma unroll
    for (int it = 0; it < 4; it++) {
      int idx = tid + it * 256;
      int row = idx >> 3, o = idx & 7;
      int g = min(pb0 + row, 2046);
      uint4 v4 = *(const uint4*)(emb + (size_t)g * 64 + o * 8);
      *(uint4*)&Pb[row * 72 + o * 8] = v4;
    }
    __syncthreads();

    // ---- S = Q K^T ----
    bf16x8 kf[4][2];
#pragma unroll
    for (int rt = 0; rt < 4; rt++)
#pragma unroll
      for (int ks = 0; ks < 2; ks++)
        kf[rt][ks] = *(const bf16x8*)&Ks[(rt * 16 + col) * 72 + quad * 8 + ks * 32];
    f32x4 sac[4];
#pragma unroll
    for (int rt = 0; rt < 4; rt++) {
      f32x4 z = (f32x4){0.f, 0.f, 0.f, 0.f};
      z = MFMA16B(qf[0], kf[rt][0], z);
      z = MFMA16B(qf[1], kf[rt][1], z);
      sac[rt] = z;
    }

    bf16x8 kaf[2];
#pragma unroll
    for (int ks = 0; ks < 2; ks++)
      kaf[ks] = *(const bf16x8*)&Ks[(lw + col) * 72 + quad * 8 + ks * 32];

    // ---- D1/D2 GEMMs + scatter into bias1/bias2 ----
#pragma unroll
    for (int dt = 0; dt < 8; dt++) {
      bf16x8 pbf0 = *(const bf16x8*)&Pb[(dt * 16 + col) * 72 + quad * 8];
      bf16x8 pbf1 = *(const bf16x8*)&Pb[(dt * 16 + col) * 72 + quad * 8 + 32];
      f32x4 z = (f32x4){0.f, 0.f, 0.f, 0.f};
      f32x4 y = (f32x4){0.f, 0.f, 0.f, 0.f};
      z = MFMA16B(qf[0], pbf0, z);
      z = MFMA16B(qf[1], pbf1, z);     // D1[l][delta]
      y = MFMA16B(kaf[0], pbf0, y);
      y = MFMA16B(kaf[1], pbf1, y);    // D2[r][delta]
      const int dcol = dt * 16 + col;
#pragma unroll
      for (int k = 0; k < 4; k++) {
        int l1 = lw + quad * 4 + k;
        int r1 = l1 - dcol + 63;
        if (r1 >= 0 && r1 < 64) B1[l1 * 66 + r1] = f2bf(z[k]);
        int r2 = lw + quad * 4 + k;
        int l2 = dcol - 63 + r2;
        if (l2 >= 0 && l2 < 64) B2[l2 * 66 + r2] = f2bf(y[k]);
      }
    }
    __syncthreads();

    // ---- online softmax ----
    float p[4][4];
    float alpha[4];
#pragma unroll
    for (int k = 0; k < 4; k++) {
      int l1 = lw + quad * 4 + k;
      float st[4];
#pragma unroll
      for (int rt = 0; rt < 4; rt++) {
        int r = rt * 16 + col;
        float bias = bf2f(B1[l1 * 66 + r]) + bf2f(B2[l1 * 66 + r]);
        st[rt] = (sac[rt][k] + bias) * 0.125f;
      }
      float mx = fmaxf(fmaxf(st[0], st[1]), fmaxf(st[2], st[3]));
      mx = fmaxf(mx, __shfl_xor(mx, 1));
      mx = fmaxf(mx, __shfl_xor(mx, 2));
      mx = fmaxf(mx, __shfl_xor(mx, 4));
      mx = fmaxf(mx, __shfl_xor(mx, 8));
      float mnew = fmaxf(mrow[k], mx);
      float a = __expf(mrow[k] - mnew);
      mrow[k] = mnew;
      alpha[k] = a;
      float ls = 0.f;
#pragma unroll
      for (int rt = 0; rt < 4; rt++) {
        p[rt][k] = __expf(st[rt] - mnew);
        ls += p[rt][k];
      }
      lrow[k] = lrow[k] * a + ls;
    }
#pragma unroll
    for (int nt = 0; nt < 4; nt++)
#pragma unroll
      for (int k = 0; k < 4; k++) oacc[nt][k] *= alpha[k];

    // ---- P -> LDS (A-layout) ----
#pragma unroll
    for (int rt = 0; rt < 4; rt++)
#pragma unroll
      for (int k = 0; k < 4; k++)
        Ps[(lw + quad * 4 + k) * 72 + rt * 16 + col] = f2bf(p[rt][k]);

    // ---- PV ----
    bf16x8 pf[2];
#pragma unroll
    for (int ks = 0; ks < 2; ks++)
      pf[ks] = *(const bf16x8*)&Ps[(lw + col) * 72 + quad * 8 + ks * 32];
#pragma unroll
    for (int nt = 0; nt < 4; nt++) {
      bf16x8 v0 = *(const bf16x8*)&VTs[(nt * 16 + col) * 72 + quad * 8];
      bf16x8 v1 = *(const bf16x8*)&VTs[(nt * 16 + col) * 72 + quad * 8 + 32];
      oacc[nt] = MFMA16B(pf[0], v0, oacc[nt]);
      oacc[nt] = MFMA16B(pf[1], v1, oacc[nt]);
    }
  }

  // ---- epilogue ----
  float inv[4];
#pragma unroll
  for (int k = 0; k < 4; k++) {
    float t = lrow[k];
    t += __shfl_xor(t, 1);
    t += __shfl_xor(t, 2);
    t += __shfl_xor(t, 4);
    t += __shfl_xor(t, 8);
    inv[k] = 1.0f / t;
  }
  const int b = bh >> 4, h = bh & 15;
#pragma unroll
  for (int nt = 0; nt < 4; nt++) {
#pragma unroll
    for (int k = 0; k < 4; k++) {
      int lg = l0 + lw + quad * 4 + k;
      int d = nt * 16 + col;
      out[(((size_t)b * Lq + lg) * Hq + h) * HDq + d] = oacc[nt][k] * inv[k];
    }
  }
}

// ---------------------------------------------------------------------------
extern "C" void kernel_launch(void* const* d_in, const int* in_sizes, int n_in,
                              void* d_out, int out_size, void* d_ws, size_t ws_size,
                              hipStream_t stream) {
  const float* x        = (const float*)d_in[0];
  const float* Wqkv     = (const float*)d_in[1];
  const float* bqkv     = (const float*)d_in[2];
  const float* dist_emb = (const float*)d_in[3];
  float* out = (float*)d_out;

  unsigned short* Xh   = (unsigned short*)d_ws;                              // 8 MB
  unsigned short* Wt   = (unsigned short*)((char*)d_ws + (8u << 20));        // 6 MB
  unsigned short* qkvg = (unsigned short*)((char*)d_ws + (16u << 20));       // 24 MB
  unsigned short* vtg  = (unsigned short*)((char*)d_ws + (40u << 20));       // 8 MB
  unsigned short* emb  = (unsigned short*)((char*)d_ws + (48u << 20));       // 256 KB

  x_prep<<<dim3(4096), dim3(256), 0, stream>>>(x, Xh);
  wt_prep<<<dim3(16, 48), dim3(256), 0, stream>>>(Wqkv, Wt);
  emb_prep<<<dim3(512), dim3(256), 0, stream>>>(dist_emb, emb);

  qkv_mfma<<<dim3(24, 32), dim3(256), 0, stream>>>(Xh, Wt, bqkv, qkvg);

  vt_prep_bf<<<dim3(BHq, Lq / 64), dim3(256), 0, stream>>>(qkvg + 2 * HEAD_ELEMS, vtg);

  attn_mfma<<<dim3(BHq, Lq / 64), dim3(256), 0, stream>>>(
      qkvg, qkvg + HEAD_ELEMS, vtg, emb, out);
}

// Round 6
// 265.225 us; speedup vs baseline: 4.7940x; 1.1158x over previous
//
#include <hip/hip_runtime.h>
#include <hip/hip_bf16.h>
#include <math.h>

// B=4, L=1024, D=1024, H=16, HD=64, SCALE=1/8
// scores[l,r] = (q.k + q.e[l-r] + k.e[l-r]) * SCALE; softmax over r; @V.
#define Bq 4
#define Lq 1024
#define Dq 1024
#define Hq 16
#define HDq 64
#define BHq (Bq * Hq)
#define HEAD_ELEMS ((size_t)BHq * Lq * HDq)   // 4194304 elements per tensor

typedef short bf16x8 __attribute__((ext_vector_type(8)));
typedef _Float16 f16x8 __attribute__((ext_vector_type(8)));
typedef float f32x4 __attribute__((ext_vector_type(4)));
#define MFMA16B(A, B, C) __builtin_amdgcn_mfma_f32_16x16x32_bf16(A, B, C, 0, 0, 0)
#define MFMA16F(A, B, C) __builtin_amdgcn_mfma_f32_16x16x32_f16(A, B, C, 0, 0, 0)

__device__ __forceinline__ unsigned short f2bf(float x) {
  unsigned u = __builtin_bit_cast(unsigned, x);
  unsigned r = u + 0x7FFFu + ((u >> 16) & 1u);   // RNE (finite inputs)
  return (unsigned short)(r >> 16);
}
__device__ __forceinline__ float bf2f(unsigned short s) {
  unsigned u = ((unsigned)s) << 16;
  return __builtin_bit_cast(float, u);
}
__device__ __forceinline__ unsigned short f2h(float x) {
  _Float16 h = (_Float16)x;                      // RNE
  return __builtin_bit_cast(unsigned short, h);
}

// ---------------------------------------------------------------------------
// P1: X fp32 -> fp16 (straight copy).  4096x1024.
// ---------------------------------------------------------------------------
__global__ __launch_bounds__(256) void x_prep(const float* __restrict__ X,
                                              unsigned short* __restrict__ Xh) {
  size_t i = (size_t)blockIdx.x * 256 + threadIdx.x;  // unit of 4 el
  float4 f = *(const float4*)(X + i * 4);
  uint2 pk;
  pk.x = (unsigned)f2h(f.x) | ((unsigned)f2h(f.y) << 16);
  pk.y = (unsigned)f2h(f.z) | ((unsigned)f2h(f.w) << 16);
  *(uint2*)(Xh + i * 4) = pk;
}

// ---------------------------------------------------------------------------
// P2: W fp32 [1024][3072] -> Wt fp16 [3072][1024] (transpose via LDS tile).
// ---------------------------------------------------------------------------
__global__ __launch_bounds__(256) void wt_prep(const float* __restrict__ W,
                                               unsigned short* __restrict__ Wt) {
  __shared__ unsigned short tile[64 * 72];
  const int k0 = blockIdx.x * 64;   // 16
  const int n0 = blockIdx.y * 64;   // 48
  const int tid = threadIdx.x;
#pragma unroll
  for (int it = 0; it < 4; it++) {
    int idx = tid + it * 256;       // 1024 units of 4 el
    int r = idx >> 4, c4 = (idx & 15) * 4;   // r = k row, c4 = n col
    float4 f = *(const float4*)(W + (size_t)(k0 + r) * 3072 + n0 + c4);
    unsigned w0 = (unsigned)f2h(f.x) | ((unsigned)f2h(f.y) << 16);
    unsigned w1 = (unsigned)f2h(f.z) | ((unsigned)f2h(f.w) << 16);
    *(unsigned*)&tile[r * 72 + c4] = w0;
    *(unsigned*)&tile[r * 72 + c4 + 2] = w1;
  }
  __syncthreads();
#pragma unroll
  for (int it = 0; it < 4; it++) {
    int u = tid + it * 256;         // 1024 units of 4 el (k-dir)
    int n = u >> 4, k4 = (u & 15) * 4;
    unsigned short e0 = tile[(k4 + 0) * 72 + n];
    unsigned short e1 = tile[(k4 + 1) * 72 + n];
    unsigned short e2 = tile[(k4 + 2) * 72 + n];
    unsigned short e3 = tile[(k4 + 3) * 72 + n];
    uint2 pk;
    pk.x = (unsigned)e0 | ((unsigned)e1 << 16);
    pk.y = (unsigned)e2 | ((unsigned)e3 << 16);
    *(uint2*)(Wt + (size_t)(n0 + n) * 1024 + k0 + k4) = pk;
  }
}

// ---------------------------------------------------------------------------
// P3: dist_emb fp32 -> bf16.
// ---------------------------------------------------------------------------
__global__ __launch_bounds__(256) void emb_prep(const float* __restrict__ e,
                                                unsigned short* __restrict__ o) {
  int i = blockIdx.x * 256 + threadIdx.x;
  if (i < 2047 * 64) o[i] = f2bf(e[i]);
}

// ---------------------------------------------------------------------------
// K1: QKV projection, fp16 MFMA (m97 structure).  Unchanged (R4-proven).
// ---------------------------------------------------------------------------
__global__ __launch_bounds__(256, 2) void qkv_mfma(
    const unsigned short* __restrict__ Xh, const unsigned short* __restrict__ Wt,
    const float* __restrict__ bias, unsigned short* __restrict__ qkvg) {
  __shared__ __align__(16) char smem[32768];
  unsigned short* Asm = (unsigned short*)smem;            // [128][32] (no pad: glds)
  unsigned short* Bsm = (unsigned short*)(smem + 8192);   // [128][32]
  unsigned short* Cs  = (unsigned short*)smem;            // epilogue [128][128]

  const int tid = threadIdx.x;
  const int w = tid >> 6, lane = tid & 63;
  const int col = lane & 15, quad = lane >> 4;
  const int wm = (w >> 1) * 64, wn = (w & 1) * 64;
  const int bn = blockIdx.x * 128, bm = blockIdx.y * 128;

  const unsigned short* Ag = Xh + (size_t)bm * 1024;
  const unsigned short* Bg = Wt + (size_t)bn * 1024;
  const int ldrow = w * 32 + (lane >> 2);   // + it*16
  const int ldoff = (lane & 3) * 8;         // element offset in k

  f32x4 acc[4][4];
#pragma unroll
  for (int i = 0; i < 4; i++)
#pragma unroll
    for (int j = 0; j < 4; j++) acc[i][j] = (f32x4){0.f, 0.f, 0.f, 0.f};

  for (int k0 = 0; k0 < 1024; k0 += 32) {
    __syncthreads();
#pragma unroll
    for (int it = 0; it < 2; it++) {
      const unsigned short* ga = Ag + (size_t)(ldrow + it * 16) * 1024 + k0 + ldoff;
      const unsigned short* gb = Bg + (size_t)(ldrow + it * 16) * 1024 + k0 + ldoff;
      __builtin_amdgcn_global_load_lds(
          (const __attribute__((address_space(1))) unsigned*)ga,
          (__attribute__((address_space(3))) unsigned*)(Asm + (w * 32 + it * 16) * 32),
          16, 0, 0);
      __builtin_amdgcn_global_load_lds(
          (const __attribute__((address_space(1))) unsigned*)gb,
          (__attribute__((address_space(3))) unsigned*)(Bsm + (w * 32 + it * 16) * 32),
          16, 0, 0);
    }
    __syncthreads();
    f16x8 af[4], bf[4];
#pragma unroll
    for (int i = 0; i < 4; i++)
      af[i] = *(const f16x8*)&Asm[(wm + i * 16 + col) * 32 + quad * 8];
#pragma unroll
    for (int j = 0; j < 4; j++)
      bf[j] = *(const f16x8*)&Bsm[(wn + j * 16 + col) * 32 + quad * 8];
#pragma unroll
    for (int i = 0; i < 4; i++)
#pragma unroll
      for (int j = 0; j < 4; j++)
        acc[i][j] = MFMA16F(af[i], bf[j], acc[i][j]);
  }

  float bj[4];
#pragma unroll
  for (int j = 0; j < 4; j++) bj[j] = bias[bn + wn + j * 16 + col];

  __syncthreads();   // staging LDS dead; reuse as Cs
#pragma unroll
  for (int i = 0; i < 4; i++)
#pragma unroll
    for (int j = 0; j < 4; j++)
#pragma unroll
      for (int k = 0; k < 4; k++)
        Cs[(wm + i * 16 + quad * 4 + k) * 128 + wn + j * 16 + col] =
            f2bf(acc[i][j][k] + bj[j]);
  __syncthreads();

  const int t = bn >> 10;                       // uniform per block
  unsigned short* dst_base = qkvg + (size_t)t * HEAD_ELEMS;
#pragma unroll
  for (int it = 0; it < 8; it++) {
    int u = tid + it * 256;                     // 2048 units of 8 el
    int row = u >> 4, c8 = (u & 15) * 8;
    int m = bm + row;
    int n = bn + c8;
    int b = m >> 10, l = m & 1023;
    int cc = n & 1023, h = cc >> 6, d0 = cc & 63;
    uint4 val = *(const uint4*)&Cs[row * 128 + c8];
    *(uint4*)(dst_base + (((size_t)(b * 16 + h) * 1024 + l) * 64 + d0)) = val;
  }
}

// ---------------------------------------------------------------------------
// P4: V bf16 [bh][l][64] -> VT bf16 [bh][d][1024].
// ---------------------------------------------------------------------------
__global__ __launch_bounds__(256) void vt_prep_bf(const unsigned short* __restrict__ vg,
                                                  unsigned short* __restrict__ vtg) {
  __shared__ unsigned short tile[64 * 72];
  const int bh = blockIdx.x;
  const int rt = blockIdx.y * 64;
  const int tid = threadIdx.x;
  const unsigned short* src = vg + ((size_t)bh * Lq + rt) * HDq;
#pragma unroll
  for (int it = 0; it < 2; it++) {
    int idx = tid + it * 256;       // 512 units of 8 el
    int r = idx >> 3, o = (idx & 7) * 8;
    *(uint4*)&tile[r * 72 + o] = *(const uint4*)(src + (size_t)r * 64 + o);
  }
  __syncthreads();
  unsigned short* dst = vtg + (size_t)bh * HDq * Lq;
#pragma unroll
  for (int it = 0; it < 4; it++) {
    int u = tid + it * 256;         // 1024 units of 4 r
    int d = u >> 4, r4 = (u & 15) * 4;
    unsigned short e0 = tile[(r4 + 0) * 72 + d];
    unsigned short e1 = tile[(r4 + 1) * 72 + d];
    unsigned short e2 = tile[(r4 + 2) * 72 + d];
    unsigned short e3 = tile[(r4 + 3) * 72 + d];
    uint2 pk;
    pk.x = (unsigned)e0 | ((unsigned)e1 << 16);
    pk.y = (unsigned)e2 | ((unsigned)e3 << 16);
    *(uint2*)(dst + (size_t)d * Lq + rt + r4) = pk;
  }
}

// ---------------------------------------------------------------------------
// K2: MFMA flash attention (R4-proven structure, 3 barriers/chunk).
// R6 deltas: (1) sliding e-band — Pb holds only the NEW 64 delta rows per
// chunk; dt 4..7 fragments carried in registers from the previous chunk
// (band overlap, values are chunk-invariant). (2) B1/B2 interleaved in one
// B12 buffer (stride 136 shorts) so softmax reads one b32 per (l,r).
// LDS 63488 B -> 2 blocks/CU.
// ---------------------------------------------------------------------------
__global__ __launch_bounds__(256, 2) void attn_mfma(
    const unsigned short* __restrict__ qg, const unsigned short* __restrict__ kg,
    const unsigned short* __restrict__ vtg, const unsigned short* __restrict__ emb,
    float* __restrict__ out) {
  __shared__ __align__(16) char smem[63488];
  unsigned short* Qs  = (unsigned short*)smem;             // [64][72]
  unsigned short* Ks  = (unsigned short*)(smem + 9216);    // [64][72]
  unsigned short* VTs = (unsigned short*)(smem + 18432);   // [64 d][72]
  unsigned short* Pb  = (unsigned short*)(smem + 27648);   // [64][72] new band half
  unsigned short* Ps  = (unsigned short*)(smem + 36864);   // [64][72]
  unsigned short* B12 = (unsigned short*)(smem + 46080);   // [64][136] interleaved

  const int bh = blockIdx.x;
  const int l0 = blockIdx.y * 64;
  const int tid = threadIdx.x;
  const int w = tid >> 6, lane = tid & 63;
  const int col = lane & 15, quad = lane >> 4;
  const int lw = w * 16;

  const unsigned short* Qg = qg + ((size_t)bh * Lq + l0) * HDq;
  const unsigned short* Kg = kg + (size_t)bh * Lq * HDq;
  const unsigned short* VTgh = vtg + (size_t)bh * HDq * Lq;

  // ---- prologue: stage Q + upper band half (delta rows 64..127 of chunk 0) ----
#pragma unroll
  for (int it = 0; it < 2; it++) {
    int idx = tid + it * 256;       // 512 units of 8 el
    int r = idx >> 3, o = (idx & 7) * 8;
    *(uint4*)&Qs[r * 72 + o] = *(const uint4*)(Qg + (size_t)r * 64 + o);
    // upper half of chunk-0 band: emb rows (l0 + 960) + 64 + r
    int g = min(l0 + 1024 + r, 2046);
    *(uint4*)&Pb[r * 72 + o] = *(const uint4*)(emb + (size_t)g * 64 + o);
  }
  __syncthreads();

  bf16x8 qf[2];
#pragma unroll
  for (int ks = 0; ks < 2; ks++)
    qf[ks] = *(const bf16x8*)&Qs[(lw + col) * 72 + quad * 8 + ks * 32];

  // carried fragments: band rows 64+dt*16+col (dt'=4..7) of the current chunk
  bf16x8 sav[4][2];
#pragma unroll
  for (int dm = 0; dm < 4; dm++)
#pragma unroll
    for (int ks = 0; ks < 2; ks++)
      sav[dm][ks] = *(const bf16x8*)&Pb[(dm * 16 + col) * 72 + quad * 8 + ks * 32];

  f32x4 oacc[4];
#pragma unroll
  for (int nt = 0; nt < 4; nt++) oacc[nt] = (f32x4){0.f, 0.f, 0.f, 0.f};
  float mrow[4] = {-1e30f, -1e30f, -1e30f, -1e30f};
  float lrow[4] = {0.f, 0.f, 0.f, 0.f};

  for (int ch = 0; ch < 16; ch++) {
    const int r0 = ch * 64;
    __syncthreads();   // prior chunk's LDS reads (incl. B12, Pb) complete

    // ---- stage K chunk ----
#pragma unroll
    for (int it = 0; it < 2; it++) {
      int idx = tid + it * 256;
      int r = idx >> 3, o = (idx & 7) * 8;
      *(uint4*)&Ks[r * 72 + o] = *(const uint4*)(Kg + (size_t)(r0 + r) * 64 + o);
    }
    // ---- stage VT chunk ----
#pragma unroll
    for (int it = 0; it < 2; it++) {
      int idx = tid + it * 256;
      int d = idx >> 3, o = (idx & 7) * 8;
      *(uint4*)&VTs[d * 72 + o] = *(const uint4*)(VTgh + (size_t)d * Lq + r0 + o);
    }
    // ---- stage NEW band half: delta rows 0..63 = emb rows pb0 + r ----
    const int pb0 = l0 - r0 + 960;
#pragma unroll
    for (int it = 0; it < 2; it++) {
      int idx = tid + it * 256;     // 512 units of 8 el
      int r = idx >> 3, o = (idx & 7) * 8;
      *(uint4*)&Pb[r * 72 + o] = *(const uint4*)(emb + (size_t)(pb0 + r) * 64 + o);
    }
    __syncthreads();   // staging visible

    // ---- S = Q K^T ----
    bf16x8 kf[4][2];
#pragma unroll
    for (int rt = 0; rt < 4; rt++)
#pragma unroll
      for (int ks = 0; ks < 2; ks++)
        kf[rt][ks] = *(const bf16x8*)&Ks[(rt * 16 + col) * 72 + quad * 8 + ks * 32];
    f32x4 sac[4];
#pragma unroll
    for (int rt = 0; rt < 4; rt++) {
      f32x4 z = (f32x4){0.f, 0.f, 0.f, 0.f};
      z = MFMA16B(qf[0], kf[rt][0], z);
      z = MFMA16B(qf[1], kf[rt][1], z);
      sac[rt] = z;
    }

    bf16x8 kaf[2];
#pragma unroll
    for (int ks = 0; ks < 2; ks++)
      kaf[ks] = *(const bf16x8*)&Ks[(lw + col) * 72 + quad * 8 + ks * 32];

    // ---- D1/D2 GEMMs + shear scatter into B12 ----
    // fresh frags (band rows dt*16+col, dt=0..3) from Pb
    bf16x8 fresh[4][2];
#pragma unroll
    for (int dm = 0; dm < 4; dm++)
#pragma unroll
      for (int ks = 0; ks < 2; ks++)
        fresh[dm][ks] = *(const bf16x8*)&Pb[(dm * 16 + col) * 72 + quad * 8 + ks * 32];

#pragma unroll
    for (int dt = 0; dt < 8; dt++) {
      bf16x8 pbf0 = (dt < 4) ? fresh[dt & 3][0] : sav[dt & 3][0];
      bf16x8 pbf1 = (dt < 4) ? fresh[dt & 3][1] : sav[dt & 3][1];
      f32x4 z = (f32x4){0.f, 0.f, 0.f, 0.f};
      f32x4 y = (f32x4){0.f, 0.f, 0.f, 0.f};
      z = MFMA16B(qf[0], pbf0, z);
      z = MFMA16B(qf[1], pbf1, z);     // D1[l][delta]
      y = MFMA16B(kaf[0], pbf0, y);
      y = MFMA16B(kaf[1], pbf1, y);    // D2[r][delta]
      const int dcol = dt * 16 + col;  // delta band index j = l - r + 63
#pragma unroll
      for (int k = 0; k < 4; k++) {
        int l1 = lw + quad * 4 + k;
        int r1 = l1 - dcol + 63;
        if (r1 >= 0 && r1 < 64) B12[l1 * 136 + 2 * r1] = f2bf(z[k]);
        int r2 = lw + quad * 4 + k;
        int l2 = dcol - 63 + r2;
        if (l2 >= 0 && l2 < 64) B12[l2 * 136 + 2 * r2 + 1] = f2bf(y[k]);
      }
    }
    // carry: this chunk's fresh lower half == next chunk's upper half
#pragma unroll
    for (int dm = 0; dm < 4; dm++)
#pragma unroll
      for (int ks = 0; ks < 2; ks++)
        sav[dm][ks] = fresh[dm][ks];
    __syncthreads();   // bias writes visible (B12 is cross-wave)

    // ---- online softmax (C-layout: row = quad*4+k, col = lane&15) ----
    float p[4][4];
    float alpha[4];
#pragma unroll
    for (int k = 0; k < 4; k++) {
      int l1 = lw + quad * 4 + k;
      float st[4];
#pragma unroll
      for (int rt = 0; rt < 4; rt++) {
        int r = rt * 16 + col;
        unsigned pr = *(const unsigned*)&B12[l1 * 136 + 2 * r];
        float bias = bf2f((unsigned short)(pr & 0xFFFFu)) +
                     bf2f((unsigned short)(pr >> 16));
        st[rt] = (sac[rt][k] + bias) * 0.125f;
      }
      float mx = fmaxf(fmaxf(st[0], st[1]), fmaxf(st[2], st[3]));
      mx = fmaxf(mx, __shfl_xor(mx, 1));
      mx = fmaxf(mx, __shfl_xor(mx, 2));
      mx = fmaxf(mx, __shfl_xor(mx, 4));
      mx = fmaxf(mx, __shfl_xor(mx, 8));
      float mnew = fmaxf(mrow[k], mx);
      float a = __expf(mrow[k] - mnew);
      mrow[k] = mnew;
      alpha[k] = a;
      float ls = 0.f;
#pragma unroll
      for (int rt = 0; rt < 4; rt++) {
        p[rt][k] = __expf(st[rt] - mnew);
        ls += p[rt][k];
      }
      lrow[k] = lrow[k] * a + ls;
    }
#pragma unroll
    for (int nt = 0; nt < 4; nt++)
#pragma unroll
      for (int k = 0; k < 4; k++) oacc[nt][k] *= alpha[k];

    // ---- P -> LDS (A-layout), same-wave rows only ----
#pragma unroll
    for (int rt = 0; rt < 4; rt++)
#pragma unroll
      for (int k = 0; k < 4; k++)
        Ps[(lw + quad * 4 + k) * 72 + rt * 16 + col] = f2bf(p[rt][k]);

    // ---- PV ----
    bf16x8 pf[2];
#pragma unroll
    for (int ks = 0; ks < 2; ks++)
      pf[ks] = *(const bf16x8*)&Ps[(lw + col) * 72 + quad * 8 + ks * 32];
#pragma unroll
    for (int nt = 0; nt < 4; nt++) {
      bf16x8 v0 = *(const bf16x8*)&VTs[(nt * 16 + col) * 72 + quad * 8];
      bf16x8 v1 = *(const bf16x8*)&VTs[(nt * 16 + col) * 72 + quad * 8 + 32];
      oacc[nt] = MFMA16B(pf[0], v0, oacc[nt]);
      oacc[nt] = MFMA16B(pf[1], v1, oacc[nt]);
    }
  }

  // ---- epilogue ----
  float inv[4];
#pragma unroll
  for (int k = 0; k < 4; k++) {
    float t = lrow[k];
    t += __shfl_xor(t, 1);
    t += __shfl_xor(t, 2);
    t += __shfl_xor(t, 4);
    t += __shfl_xor(t, 8);
    inv[k] = 1.0f / t;
  }
  const int b = bh >> 4, h = bh & 15;
#pragma unroll
  for (int nt = 0; nt < 4; nt++) {
#pragma unroll
    for (int k = 0; k < 4; k++) {
      int lg = l0 + lw + quad * 4 + k;
      int d = nt * 16 + col;
      out[(((size_t)b * Lq + lg) * Hq + h) * HDq + d] = oacc[nt][k] * inv[k];
    }
  }
}

// ---------------------------------------------------------------------------
extern "C" void kernel_launch(void* const* d_in, const int* in_sizes, int n_in,
                              void* d_out, int out_size, void* d_ws, size_t ws_size,
                              hipStream_t stream) {
  const float* x        = (const float*)d_in[0];
  const float* Wqkv     = (const float*)d_in[1];
  const float* bqkv     = (const float*)d_in[2];
  const float* dist_emb = (const float*)d_in[3];
  float* out = (float*)d_out;

  unsigned short* Xh   = (unsigned short*)d_ws;                              // 8 MB
  unsigned short* Wt   = (unsigned short*)((char*)d_ws + (8u << 20));        // 6 MB
  unsigned short* qkvg = (unsigned short*)((char*)d_ws + (16u << 20));       // 24 MB
  unsigned short* vtg  = (unsigned short*)((char*)d_ws + (40u << 20));       // 8 MB
  unsigned short* emb  = (unsigned short*)((char*)d_ws + (48u << 20));       // 256 KB

  x_prep<<<dim3(4096), dim3(256), 0, stream>>>(x, Xh);
  wt_prep<<<dim3(16, 48), dim3(256), 0, stream>>>(Wqkv, Wt);
  emb_prep<<<dim3(512), dim3(256), 0, stream>>>(dist_emb, emb);

  qkv_mfma<<<dim3(24, 32), dim3(256), 0, stream>>>(Xh, Wt, bqkv, qkvg);

  vt_prep_bf<<<dim3(BHq, Lq / 64), dim3(256), 0, stream>>>(qkvg + 2 * HEAD_ELEMS, vtg);

  attn_mfma<<<dim3(BHq, Lq / 64), dim3(256), 0, stream>>>(
      qkvg, qkvg + HEAD_ELEMS, vtg, emb, out);
}